// Round 5
// baseline (215.253 us; speedup 1.0000x reference)
//
#include <hip/hip_runtime.h>

#define DDIM 256
#define HDIM 128
#define KLEN 1024
// 2*log2(e): exp2(SCL*(qW+kW)) == e^{2(qW+kW)} -> tanh via rcp, no mul in hot loop
#define SCL 2.8853900817779268f

// ============ Projection (LDS-free main loop) ============
// q2/k2T = SCL * (in @ W).  Blocks 0..511: keys (XCD-swizzled b), 32 rows each,
// output transposed k2T[b][h][k]. Blocks 512..543: queries -> q2[bq][h] row-major.
// Block: 4 waves; wave w = rows w*8..w*8+7; lane -> h = 2*lane (W loads coalesced).
__global__ __launch_bounds__(256) void proj_kernel(
    const float* __restrict__ queries, const float* __restrict__ keys,
    const float* __restrict__ W_q, const float* __restrict__ W_k,
    float* __restrict__ q2, float* __restrict__ k2T)
{
    __shared__ float T[HDIM][33];   // 16.9 KB, keys-transpose staging (epilogue only)

    int tid = threadIdx.x, lane = tid & 63, w = tid >> 6;
    int blk = blockIdx.x;
    bool iskey = blk < 512;
    const float* in; const float* W; int row0, b = 0;
    if (iskey) {
        int xcd = blk & 7, s = blk >> 3;          // same swizzle as score/av:
        b = xcd + ((s >= 32) ? 8 : 0);            // batch b lives on XCD b%8
        row0 = b * KLEN + (s & 31) * 32;
        in = keys; W = W_k;
    } else {
        row0 = (blk - 512) * 32;
        in = queries; W = W_q;
    }

    int h = lane << 1;
    const float* inrow = in + (size_t)(row0 + w * 8) * DDIM;

    float2 acc[8];
    #pragma unroll
    for (int j = 0; j < 8; j++) acc[j] = make_float2(0.f, 0.f);

    #pragma unroll 2
    for (int d = 0; d < DDIM; d += 4) {
        const float* wp = W + (size_t)d * HDIM + h;
        float2 w0 = *(const float2*)(wp);
        float2 w1 = *(const float2*)(wp + HDIM);
        float2 w2 = *(const float2*)(wp + 2 * HDIM);
        float2 w3 = *(const float2*)(wp + 3 * HDIM);
        #pragma unroll
        for (int j = 0; j < 8; j++) {
            float4 a = *(const float4*)(inrow + (size_t)j * DDIM + d);
            acc[j].x = fmaf(a.x, w0.x, acc[j].x); acc[j].y = fmaf(a.x, w0.y, acc[j].y);
            acc[j].x = fmaf(a.y, w1.x, acc[j].x); acc[j].y = fmaf(a.y, w1.y, acc[j].y);
            acc[j].x = fmaf(a.z, w2.x, acc[j].x); acc[j].y = fmaf(a.z, w2.y, acc[j].y);
            acc[j].x = fmaf(a.w, w3.x, acc[j].x); acc[j].y = fmaf(a.w, w3.y, acc[j].y);
        }
    }
    #pragma unroll
    for (int j = 0; j < 8; j++) { acc[j].x *= SCL; acc[j].y *= SCL; }

    if (!iskey) {
        #pragma unroll
        for (int j = 0; j < 8; j++)
            *(float2*)(q2 + (size_t)(row0 + w * 8 + j) * HDIM + h) = acc[j];
    } else {
        #pragma unroll
        for (int j = 0; j < 8; j++) {
            T[h][w * 8 + j]     = acc[j].x;
            T[h + 1][w * 8 + j] = acc[j].y;
        }
        __syncthreads();
        int kc0 = row0 & (KLEN - 1);
        float* dst = k2T + (size_t)b * HDIM * KLEN + kc0;
        #pragma unroll
        for (int i = tid; i < HDIM * 8; i += 256) {   // 1024 float4 slots
            int hh = i >> 3, c = (i & 7) << 2;
            float4 o = make_float4(T[hh][c], T[hh][c + 1], T[hh][c + 2], T[hh][c + 3]);
            *(float4*)(dst + (size_t)hh * KLEN + c) = o;
        }
    }
}

// ============ Scores + masked softmax, 2 queries per block ============
// Grid 512, XCD-swizzled. thread = k; k2T reads coalesced & L2-local; each
// k-element serves both queries. Writes fully-normalized p (masked k -> 0).
__global__ __launch_bounds__(256) void score_kernel(
    const float* __restrict__ q2, const float* __restrict__ k2T,
    const float* __restrict__ w_v, const int* __restrict__ valid_lens,
    float* __restrict__ p)
{
    __shared__ float qw[2 * HDIM];
    __shared__ float w2l[HDIM];
    __shared__ float sc[2][KLEN];
    __shared__ float red[8];

    int tid = threadIdx.x, lane = tid & 63, wav = tid >> 6;
    int blk = blockIdx.x;
    int xcd = blk & 7, s = blk >> 3;
    int b = xcd + ((s >= 32) ? 8 : 0);
    int qp = s & 31;
    int bq0 = b * 64 + qp * 2;
    int vlen = valid_lens[b];

    if (tid < 2 * HDIM) qw[tid] = q2[(size_t)bq0 * HDIM + tid];
    if (tid < HDIM) w2l[tid] = -2.0f * w_v[tid];
    __syncthreads();

    const float* kb = k2T + (size_t)b * HDIM * KLEN;

    #pragma unroll
    for (int kt = 0; kt < 4; kt++) {
        int k = kt * 256 + tid;
        float s0 = -1e30f, s1 = -1e30f;
        if (k < vlen) {
            const float* kp = kb + k;
            s0 = 0.f; s1 = 0.f;
            #pragma unroll 4
            for (int hh = 0; hh < HDIM; hh += 4) {
                float4 qa = *(const float4*)(&qw[hh]);
                float4 qb = *(const float4*)(&qw[HDIM + hh]);
                float4 ww = *(const float4*)(&w2l[hh]);
                float k0 = kp[(size_t)(hh + 0) * KLEN];
                float k1 = kp[(size_t)(hh + 1) * KLEN];
                float k2 = kp[(size_t)(hh + 2) * KLEN];
                float k3 = kp[(size_t)(hh + 3) * KLEN];
                s0 = fmaf(ww.x, __builtin_amdgcn_rcpf(__builtin_amdgcn_exp2f(qa.x + k0) + 1.f), s0);
                s0 = fmaf(ww.y, __builtin_amdgcn_rcpf(__builtin_amdgcn_exp2f(qa.y + k1) + 1.f), s0);
                s0 = fmaf(ww.z, __builtin_amdgcn_rcpf(__builtin_amdgcn_exp2f(qa.z + k2) + 1.f), s0);
                s0 = fmaf(ww.w, __builtin_amdgcn_rcpf(__builtin_amdgcn_exp2f(qa.w + k3) + 1.f), s0);
                s1 = fmaf(ww.x, __builtin_amdgcn_rcpf(__builtin_amdgcn_exp2f(qb.x + k0) + 1.f), s1);
                s1 = fmaf(ww.y, __builtin_amdgcn_rcpf(__builtin_amdgcn_exp2f(qb.y + k1) + 1.f), s1);
                s1 = fmaf(ww.z, __builtin_amdgcn_rcpf(__builtin_amdgcn_exp2f(qb.z + k2) + 1.f), s1);
                s1 = fmaf(ww.w, __builtin_amdgcn_rcpf(__builtin_amdgcn_exp2f(qb.w + k3) + 1.f), s1);
            }
        }
        sc[0][k] = s0;
        sc[1][k] = s1;
    }
    __syncthreads();

    float m0 = -1e30f, m1 = -1e30f;
    #pragma unroll
    for (int i = 0; i < 4; i++) {
        m0 = fmaxf(m0, sc[0][tid + 256 * i]);
        m1 = fmaxf(m1, sc[1][tid + 256 * i]);
    }
    #pragma unroll
    for (int off = 32; off > 0; off >>= 1) {
        m0 = fmaxf(m0, __shfl_xor(m0, off, 64));
        m1 = fmaxf(m1, __shfl_xor(m1, off, 64));
    }
    if (lane == 0) { red[wav] = m0; red[4 + wav] = m1; }
    __syncthreads();
    m0 = fmaxf(fmaxf(red[0], red[1]), fmaxf(red[2], red[3]));
    m1 = fmaxf(fmaxf(red[4], red[5]), fmaxf(red[6], red[7]));

    float e0[4], e1[4];
    float t0 = 0.f, t1 = 0.f;
    #pragma unroll
    for (int i = 0; i < 4; i++) {
        e0[i] = __expf(sc[0][tid + 256 * i] - m0);
        e1[i] = __expf(sc[1][tid + 256 * i] - m1);
        t0 += e0[i]; t1 += e1[i];
    }
    #pragma unroll
    for (int off = 32; off > 0; off >>= 1) {
        t0 += __shfl_xor(t0, off, 64);
        t1 += __shfl_xor(t1, off, 64);
    }
    __syncthreads();   // red max-reads done before rewrite
    if (lane == 0) { red[wav] = t0; red[4 + wav] = t1; }
    __syncthreads();
    float inv0 = 1.0f / (red[0] + red[1] + red[2] + red[3]);
    float inv1 = 1.0f / (red[4] + red[5] + red[6] + red[7]);

    float* p0 = p + (size_t)bq0 * KLEN;
    float* p1 = p0 + KLEN;
    #pragma unroll
    for (int i = 0; i < 4; i++) {
        p0[tid + 256 * i] = e0[i] * inv0;   // masked: exp(-1e30-m)=0 -> exact 0
        p1[tid + 256 * i] = e1[i] * inv1;
    }
}

// ============ attn @ V: 8 queries, k-quarter per block ============
// Grid 512, XCD-swizzled. thread = d (V coalesced); p loads wave-uniform
// (scalar pipe). Always stores -> poison-safe.
__global__ __launch_bounds__(256) void av_kernel(
    const float* __restrict__ p, const float* __restrict__ values,
    const int* __restrict__ valid_lens, float* __restrict__ part)
{
    int blk = blockIdx.x;
    int xcd = blk & 7, s = blk >> 3;
    int b = xcd + ((s >= 32) ? 8 : 0);
    int r = s & 31, qt = r >> 2, kq = r & 3;
    int tid = threadIdx.x;
    int vlen = valid_lens[b];
    int kbeg = kq << 8;
    int kc = vlen - kbeg; kc = kc < 0 ? 0 : (kc > 256 ? 256 : kc);
    int bq0 = b * 64 + qt * 8;

    const float* vb = values + ((size_t)b * KLEN + kbeg) * DDIM + tid;
    const float* p0 = p + (size_t)bq0 * KLEN + kbeg;

    float acc[8];
    #pragma unroll
    for (int q = 0; q < 8; q++) acc[q] = 0.f;

    int k = 0;
    for (; k + 3 < kc; k += 4) {
        float v0 = vb[(size_t)(k + 0) * DDIM];
        float v1 = vb[(size_t)(k + 1) * DDIM];
        float v2 = vb[(size_t)(k + 2) * DDIM];
        float v3 = vb[(size_t)(k + 3) * DDIM];
        #pragma unroll
        for (int q = 0; q < 8; q++) {
            const float* pq = p0 + (size_t)q * KLEN + k;
            acc[q] = fmaf(pq[0], v0, acc[q]);
            acc[q] = fmaf(pq[1], v1, acc[q]);
            acc[q] = fmaf(pq[2], v2, acc[q]);
            acc[q] = fmaf(pq[3], v3, acc[q]);
        }
    }
    for (; k < kc; k++) {
        float v = vb[(size_t)k * DDIM];
        #pragma unroll
        for (int q = 0; q < 8; q++)
            acc[q] = fmaf(p0[(size_t)q * KLEN + k], v, acc[q]);
    }
    float* pt = part + ((size_t)kq * 1024 + bq0) * DDIM + tid;
    #pragma unroll
    for (int q = 0; q < 8; q++)
        pt[(size_t)q * DDIM] = acc[q];
}

__global__ __launch_bounds__(256) void combine_kernel(
    const float* __restrict__ part, float* __restrict__ out)
{
    size_t i = (size_t)blockIdx.x * DDIM + threadIdx.x;
    const size_t STR = (size_t)1024 * DDIM;
    out[i] = (part[i] + part[STR + i]) + (part[2 * STR + i] + part[3 * STR + i]);
}

extern "C" void kernel_launch(void* const* d_in, const int* in_sizes, int n_in,
                              void* d_out, int out_size, void* d_ws, size_t ws_size,
                              hipStream_t stream) {
    const float* queries    = (const float*)d_in[0]; // [16,64,256]
    const float* keys       = (const float*)d_in[1]; // [16,1024,256]
    const float* values     = (const float*)d_in[2]; // [16,1024,256]
    const int*   valid_lens = (const int*)d_in[3];   // [16]
    const float* W_q        = (const float*)d_in[4]; // [256,128]
    const float* W_k        = (const float*)d_in[5]; // [256,128]
    const float* w_v        = (const float*)d_in[6]; // [128]

    float* q2   = (float*)d_ws;            // 1024*128     = 512 KB
    float* k2T  = q2 + 131072;             // 16*128*1024  = 8 MB
    float* p    = k2T + 2097152;           // 1024*1024    = 4 MB
    float* part = k2T;                     // alias: k2T dead after score (4 MB used)

    proj_kernel<<<544, 256, 0, stream>>>(queries, keys, W_q, W_k, q2, k2T);
    score_kernel<<<512, 256, 0, stream>>>(q2, k2T, w_v, valid_lens, p);
    av_kernel<<<512, 256, 0, stream>>>(p, values, valid_lens, part);
    combine_kernel<<<1024, 256, 0, stream>>>(part, (float*)d_out);
}

// Round 6
// 206.704 us; speedup vs baseline: 1.0414x; 1.0414x over previous
//
#include <hip/hip_runtime.h>

#define DDIM 256
#define HDIM 128
#define KLEN 1024
// 2*log2(e): exp2(SCL*(qW+kW)) == e^{2(qW+kW)}
#define SCL 2.8853900817779268f

// ============ Projection ============
// q2/k2T = SCL * (in @ W).  Tile: 32 rows x 64 h (h-half). Grid 1088:
// blocks 0..1023 = keys (XCD-swizzled: batch b on xcd b&7), 1024..1087 = queries.
// 256 threads = 8 row-groups(x4 rows) x 32 h-pairs. W d-tile (64x64=16KB) in LDS,
// read as b64 (2-way bank = free). 4 rows/thread -> 4 FMA per W-float.
__global__ __launch_bounds__(256) void proj_kernel(
    const float* __restrict__ queries, const float* __restrict__ keys,
    const float* __restrict__ W_q, const float* __restrict__ W_k,
    float* __restrict__ q2, float* __restrict__ k2T)
{
    __shared__ union {
        float w[64][64];   // 16 KB W-tile
        float t[64][33];   // transpose staging (epilogue only, fits inside)
    } sm;

    int tid = threadIdx.x;
    int hg = tid & 31;     // h-pair index
    int rg = tid >> 5;     // row-group (4 rows each)
    int blk = blockIdx.x;

    const float* in; const float* W; int row0, hbase, b = 0, kc0 = 0; bool iskey;
    if (blk < 1024) {
        iskey = true;
        int xcd = blk & 7, s = blk >> 3;
        b = ((s >> 6) << 3) | xcd;     // batch; consecutive blks spread over XCDs
        int r6 = s & 63;
        kc0   = (r6 >> 1) * 32;        // k-offset within batch
        hbase = (r6 & 1) << 6;         // h-half: 0 or 64
        row0  = b * KLEN + kc0;
        in = keys; W = W_k;
    } else {
        iskey = false;
        int qrb = blk - 1024;          // 0..63
        row0  = (qrb >> 1) * 32;
        hbase = (qrb & 1) << 6;
        in = queries; W = W_q;
    }

    float2 acc[4];
    #pragma unroll
    for (int j = 0; j < 4; j++) acc[j] = make_float2(0.f, 0.f);

    for (int dt = 0; dt < DDIM; dt += 64) {
        __syncthreads();
        #pragma unroll
        for (int i = 0; i < 4; i++) {           // stage W[dt..+63][hbase..+63]
            int idx = tid + 256 * i;            // 1024 float4 slots
            int dd = idx >> 4, hl = (idx & 15) << 2;
            *(float4*)(&sm.w[dd][hl]) =
                *(const float4*)(W + (size_t)(dt + dd) * HDIM + hbase + hl);
        }
        __syncthreads();

        #pragma unroll 2
        for (int d4 = 0; d4 < 64; d4 += 4) {
            float2 wr[4];
            #pragma unroll
            for (int dd = 0; dd < 4; dd++)
                wr[dd] = *(const float2*)(&sm.w[d4 + dd][hg << 1]);
            #pragma unroll
            for (int j = 0; j < 4; j++) {
                float4 a = *(const float4*)(in + (size_t)(row0 + rg * 4 + j) * DDIM + dt + d4);
                acc[j].x = fmaf(a.x, wr[0].x, acc[j].x); acc[j].y = fmaf(a.x, wr[0].y, acc[j].y);
                acc[j].x = fmaf(a.y, wr[1].x, acc[j].x); acc[j].y = fmaf(a.y, wr[1].y, acc[j].y);
                acc[j].x = fmaf(a.z, wr[2].x, acc[j].x); acc[j].y = fmaf(a.z, wr[2].y, acc[j].y);
                acc[j].x = fmaf(a.w, wr[3].x, acc[j].x); acc[j].y = fmaf(a.w, wr[3].y, acc[j].y);
            }
        }
    }
    #pragma unroll
    for (int j = 0; j < 4; j++) { acc[j].x *= SCL; acc[j].y *= SCL; }

    if (!iskey) {
        #pragma unroll
        for (int j = 0; j < 4; j++)
            *(float2*)(q2 + (size_t)(row0 + rg * 4 + j) * HDIM + hbase + (hg << 1)) = acc[j];
    } else {
        __syncthreads();               // done reading sm.w
        #pragma unroll
        for (int j = 0; j < 4; j++) {  // t[h_local][k_local]
            sm.t[(hg << 1) + 0][rg * 4 + j] = acc[j].x;
            sm.t[(hg << 1) + 1][rg * 4 + j] = acc[j].y;
        }
        __syncthreads();
        float* dst = k2T + (size_t)b * HDIM * KLEN + (size_t)hbase * KLEN + kc0;
        #pragma unroll
        for (int i = 0; i < 2; i++) {  // 512 float4 stores: 64 h x 32 k
            int idx = tid + 256 * i;
            int hh = idx >> 3, c = (idx & 7) << 2;
            float4 o = make_float4(sm.t[hh][c], sm.t[hh][c + 1],
                                   sm.t[hh][c + 2], sm.t[hh][c + 3]);
            *(float4*)(dst + (size_t)hh * KLEN + c) = o;
        }
    }
}

// ============ Scores + masked softmax, 2 queries per block ============
// Grid 512, XCD-swizzled. thread = k; k2T loads coalesced; q2/w_v via uniform
// addresses -> s_load (SGPR), zero LDS in hot loop. Skips k-tiles >= vlen.
__global__ __launch_bounds__(256) void score_kernel(
    const float* __restrict__ q2, const float* __restrict__ k2T,
    const float* __restrict__ w_v, const int* __restrict__ valid_lens,
    float* __restrict__ p)
{
    __shared__ float sc[2][KLEN];
    __shared__ float red[8];

    int tid = threadIdx.x, lane = tid & 63, wav = tid >> 6;
    int blk = blockIdx.x;
    int xcd = blk & 7, s = blk >> 3;
    int b = ((s >= 32) ? 8 : 0) + xcd;
    int qp = s & 31;
    int bq0 = b * 64 + qp * 2;
    int vlen = valid_lens[b];
    int ktmax = (vlen + 255) >> 8;     // 1..4

    const float* kb   = k2T + (size_t)b * HDIM * KLEN;
    const float* qa_p = q2 + (size_t)bq0 * HDIM;
    const float* qb_p = qa_p + HDIM;

    for (int kt = 0; kt < ktmax; kt++) {
        int k = kt * 256 + tid;
        const float* kp = kb + k;
        float s0 = 0.f, s1 = 0.f;
        #pragma unroll
        for (int hh = 0; hh < HDIM; hh += 4) {
            float4 qa = *(const float4*)(qa_p + hh);   // uniform -> s_load
            float4 qb = *(const float4*)(qb_p + hh);
            float4 ww = *(const float4*)(w_v + hh);
            float k0 = kp[(size_t)(hh + 0) * KLEN];
            float k1 = kp[(size_t)(hh + 1) * KLEN];
            float k2 = kp[(size_t)(hh + 2) * KLEN];
            float k3 = kp[(size_t)(hh + 3) * KLEN];
            s0 = fmaf(ww.x, __builtin_amdgcn_rcpf(__builtin_amdgcn_exp2f(qa.x + k0) + 1.f), s0);
            s0 = fmaf(ww.y, __builtin_amdgcn_rcpf(__builtin_amdgcn_exp2f(qa.y + k1) + 1.f), s0);
            s0 = fmaf(ww.z, __builtin_amdgcn_rcpf(__builtin_amdgcn_exp2f(qa.z + k2) + 1.f), s0);
            s0 = fmaf(ww.w, __builtin_amdgcn_rcpf(__builtin_amdgcn_exp2f(qa.w + k3) + 1.f), s0);
            s1 = fmaf(ww.x, __builtin_amdgcn_rcpf(__builtin_amdgcn_exp2f(qb.x + k0) + 1.f), s1);
            s1 = fmaf(ww.y, __builtin_amdgcn_rcpf(__builtin_amdgcn_exp2f(qb.y + k1) + 1.f), s1);
            s1 = fmaf(ww.z, __builtin_amdgcn_rcpf(__builtin_amdgcn_exp2f(qb.z + k2) + 1.f), s1);
            s1 = fmaf(ww.w, __builtin_amdgcn_rcpf(__builtin_amdgcn_exp2f(qb.w + k3) + 1.f), s1);
        }
        // score' = -2 * sum w*r  (softmax-shift-equivalent to sum w*tanh)
        sc[0][k] = (k < vlen) ? -2.f * s0 : -1e30f;
        sc[1][k] = (k < vlen) ? -2.f * s1 : -1e30f;
    }
    for (int kt = ktmax; kt < 4; kt++) {
        sc[0][kt * 256 + tid] = -1e30f;
        sc[1][kt * 256 + tid] = -1e30f;
    }
    __syncthreads();

    float m0 = -1e30f, m1 = -1e30f;
    #pragma unroll
    for (int i = 0; i < 4; i++) {
        m0 = fmaxf(m0, sc[0][tid + 256 * i]);
        m1 = fmaxf(m1, sc[1][tid + 256 * i]);
    }
    #pragma unroll
    for (int off = 32; off > 0; off >>= 1) {
        m0 = fmaxf(m0, __shfl_xor(m0, off, 64));
        m1 = fmaxf(m1, __shfl_xor(m1, off, 64));
    }
    if (lane == 0) { red[wav] = m0; red[4 + wav] = m1; }
    __syncthreads();
    m0 = fmaxf(fmaxf(red[0], red[1]), fmaxf(red[2], red[3]));
    m1 = fmaxf(fmaxf(red[4], red[5]), fmaxf(red[6], red[7]));

    float e0[4], e1[4], t0 = 0.f, t1 = 0.f;
    #pragma unroll
    for (int i = 0; i < 4; i++) {
        e0[i] = __expf(sc[0][tid + 256 * i] - m0);   // masked: exp(-1e30-m)=0
        e1[i] = __expf(sc[1][tid + 256 * i] - m1);
        t0 += e0[i]; t1 += e1[i];
    }
    #pragma unroll
    for (int off = 32; off > 0; off >>= 1) {
        t0 += __shfl_xor(t0, off, 64);
        t1 += __shfl_xor(t1, off, 64);
    }
    __syncthreads();
    if (lane == 0) { red[wav] = t0; red[4 + wav] = t1; }
    __syncthreads();
    float inv0 = 1.0f / (red[0] + red[1] + red[2] + red[3]);
    float inv1 = 1.0f / (red[4] + red[5] + red[6] + red[7]);

    float* p0 = p + (size_t)bq0 * KLEN;
    float* p1 = p0 + KLEN;
    #pragma unroll
    for (int i = 0; i < 4; i++) {
        p0[tid + 256 * i] = e0[i] * inv0;
        p1[tid + 256 * i] = e1[i] * inv1;
    }
}

// ============ attn @ V ============
// Grid 1024 = (16 b XCD-swizzled) x (8 q-tiles of 8) x (8 k-eighths of 128).
// Wave owns 2 q; lanes own d4 -> float4 V loads; p via uniform s_load (SGPR
// operand into v_fma). Always stores -> poison-safe.
__global__ __launch_bounds__(256) void av_kernel(
    const float* __restrict__ p, const float* __restrict__ values,
    const int* __restrict__ valid_lens, float* __restrict__ part)
{
    int blk = blockIdx.x;
    int xcd = blk & 7, s = blk >> 3;
    int b = ((s >> 6) << 3) | xcd;
    int r = s & 63, qt = r >> 3, kq = r & 7;
    int tid = threadIdx.x, lane = tid & 63, w = tid >> 6;
    int vlen = valid_lens[b];
    int kbeg = kq << 7;
    int kc = vlen - kbeg; kc = kc < 0 ? 0 : (kc > 128 ? 128 : kc);
    int bq0 = b * 64 + qt * 8;

    const float* vb  = values + ((size_t)b * KLEN + kbeg) * DDIM + (lane << 2);
    const float* pq0 = p + (size_t)(bq0 + 2 * w) * KLEN + kbeg;   // uniform
    const float* pq1 = pq0 + KLEN;

    float4 a0 = make_float4(0.f, 0.f, 0.f, 0.f);
    float4 a1 = make_float4(0.f, 0.f, 0.f, 0.f);

    int k = 0;
    for (; k + 3 < kc; k += 4) {
        float4 v0 = *(const float4*)(vb + (size_t)(k + 0) * DDIM);
        float4 v1 = *(const float4*)(vb + (size_t)(k + 1) * DDIM);
        float4 v2 = *(const float4*)(vb + (size_t)(k + 2) * DDIM);
        float4 v3 = *(const float4*)(vb + (size_t)(k + 3) * DDIM);
        float pa0 = pq0[k], pa1 = pq0[k + 1], pa2 = pq0[k + 2], pa3 = pq0[k + 3];
        float pb0 = pq1[k], pb1 = pq1[k + 1], pb2 = pq1[k + 2], pb3 = pq1[k + 3];
        a0.x = fmaf(pa0, v0.x, a0.x); a0.y = fmaf(pa0, v0.y, a0.y);
        a0.z = fmaf(pa0, v0.z, a0.z); a0.w = fmaf(pa0, v0.w, a0.w);
        a0.x = fmaf(pa1, v1.x, a0.x); a0.y = fmaf(pa1, v1.y, a0.y);
        a0.z = fmaf(pa1, v1.z, a0.z); a0.w = fmaf(pa1, v1.w, a0.w);
        a0.x = fmaf(pa2, v2.x, a0.x); a0.y = fmaf(pa2, v2.y, a0.y);
        a0.z = fmaf(pa2, v2.z, a0.z); a0.w = fmaf(pa2, v2.w, a0.w);
        a0.x = fmaf(pa3, v3.x, a0.x); a0.y = fmaf(pa3, v3.y, a0.y);
        a0.z = fmaf(pa3, v3.z, a0.z); a0.w = fmaf(pa3, v3.w, a0.w);
        a1.x = fmaf(pb0, v0.x, a1.x); a1.y = fmaf(pb0, v0.y, a1.y);
        a1.z = fmaf(pb0, v0.z, a1.z); a1.w = fmaf(pb0, v0.w, a1.w);
        a1.x = fmaf(pb1, v1.x, a1.x); a1.y = fmaf(pb1, v1.y, a1.y);
        a1.z = fmaf(pb1, v1.z, a1.z); a1.w = fmaf(pb1, v1.w, a1.w);
        a1.x = fmaf(pb2, v2.x, a1.x); a1.y = fmaf(pb2, v2.y, a1.y);
        a1.z = fmaf(pb2, v2.z, a1.z); a1.w = fmaf(pb2, v2.w, a1.w);
        a1.x = fmaf(pb3, v3.x, a1.x); a1.y = fmaf(pb3, v3.y, a1.y);
        a1.z = fmaf(pb3, v3.z, a1.z); a1.w = fmaf(pb3, v3.w, a1.w);
    }
    for (; k < kc; k++) {
        float4 v = *(const float4*)(vb + (size_t)k * DDIM);
        float pa = pq0[k], pb = pq1[k];
        a0.x = fmaf(pa, v.x, a0.x); a0.y = fmaf(pa, v.y, a0.y);
        a0.z = fmaf(pa, v.z, a0.z); a0.w = fmaf(pa, v.w, a0.w);
        a1.x = fmaf(pb, v.x, a1.x); a1.y = fmaf(pb, v.y, a1.y);
        a1.z = fmaf(pb, v.z, a1.z); a1.w = fmaf(pb, v.w, a1.w);
    }
    float* d0 = part + ((size_t)kq * 1024 + bq0 + 2 * w) * DDIM + (lane << 2);
    *(float4*)(d0)        = a0;
    *(float4*)(d0 + DDIM) = a1;
}

// ============ sum 8 k-partials ============
__global__ __launch_bounds__(256) void combine_kernel(
    const float* __restrict__ part, float* __restrict__ out)
{
    int i = blockIdx.x * 256 + threadIdx.x;        // 65536 float4 slots
    const float4* p4 = (const float4*)part;
    float4 a = p4[i];
    #pragma unroll
    for (int j = 1; j < 8; j++) {
        float4 v = p4[(size_t)j * 65536 + i];
        a.x += v.x; a.y += v.y; a.z += v.z; a.w += v.w;
    }
    ((float4*)out)[i] = a;
}

extern "C" void kernel_launch(void* const* d_in, const int* in_sizes, int n_in,
                              void* d_out, int out_size, void* d_ws, size_t ws_size,
                              hipStream_t stream) {
    const float* queries    = (const float*)d_in[0]; // [16,64,256]
    const float* keys       = (const float*)d_in[1]; // [16,1024,256]
    const float* values     = (const float*)d_in[2]; // [16,1024,256]
    const int*   valid_lens = (const int*)d_in[3];   // [16]
    const float* W_q        = (const float*)d_in[4]; // [256,128]
    const float* W_k        = (const float*)d_in[5]; // [256,128]
    const float* w_v        = (const float*)d_in[6]; // [128]

    float* q2   = (float*)d_ws;            // 1024*128     = 512 KB
    float* k2T  = q2 + 131072;             // 16*128*1024  = 8 MB
    float* p    = k2T + 2097152;           // 1024*1024    = 4 MB
    float* part = k2T;                     // alias: k2T dead after score; 8 MB exact

    proj_kernel<<<1088, 256, 0, stream>>>(queries, keys, W_q, W_k, q2, k2T);
    score_kernel<<<512, 256, 0, stream>>>(q2, k2T, w_v, valid_lens, p);
    av_kernel<<<1024, 256, 0, stream>>>(p, values, valid_lens, part);
    combine_kernel<<<256, 256, 0, stream>>>(part, (float*)d_out);
}

// Round 7
// 166.532 us; speedup vs baseline: 1.2926x; 1.2412x over previous
//
#include <hip/hip_runtime.h>

#define DDIM 256
#define HDIM 128
#define KLEN 1024
// 2*log2(e): exp2(SCL*x) == e^{2x}
#define SCL 2.8853900817779268f

// ============ Projection -> Eq/Ek = exp2(SCL * in@W) ============
// Tile: 32 rows x 64 h. Grid 1088: blocks 0..1023 keys (XCD-swizzled),
// 1024..1087 queries. W d-tile in LDS (b64 reads, 2-way = free).
// Epilogue applies exp2 so the score kernel needs no exp at all.
__global__ __launch_bounds__(256) void proj_kernel(
    const float* __restrict__ queries, const float* __restrict__ keys,
    const float* __restrict__ W_q, const float* __restrict__ W_k,
    float* __restrict__ Eq, float* __restrict__ Ek)
{
    __shared__ union {
        float w[64][64];   // 16 KB W-tile
        float t[64][33];   // transpose staging (epilogue only)
    } sm;

    int tid = threadIdx.x;
    int hg = tid & 31;     // h-pair index
    int rg = tid >> 5;     // row-group (4 rows)
    int blk = blockIdx.x;

    const float* in; const float* W; int row0, hbase, b = 0, kc0 = 0; bool iskey;
    if (blk < 1024) {
        iskey = true;
        int xcd = blk & 7, s = blk >> 3;
        b = ((s >> 6) << 3) | xcd;
        int r6 = s & 63;
        kc0   = (r6 >> 1) * 32;
        hbase = (r6 & 1) << 6;
        row0  = b * KLEN + kc0;
        in = keys; W = W_k;
    } else {
        iskey = false;
        int qrb = blk - 1024;
        row0  = (qrb >> 1) * 32;
        hbase = (qrb & 1) << 6;
        in = queries; W = W_q;
    }

    float2 acc[4];
    #pragma unroll
    for (int j = 0; j < 4; j++) acc[j] = make_float2(0.f, 0.f);

    for (int dt = 0; dt < DDIM; dt += 64) {
        __syncthreads();
        #pragma unroll
        for (int i = 0; i < 4; i++) {
            int idx = tid + 256 * i;
            int dd = idx >> 4, hl = (idx & 15) << 2;
            *(float4*)(&sm.w[dd][hl]) =
                *(const float4*)(W + (size_t)(dt + dd) * HDIM + hbase + hl);
        }
        __syncthreads();

        #pragma unroll 4
        for (int d4 = 0; d4 < 64; d4 += 4) {
            float2 wr[4];
            #pragma unroll
            for (int dd = 0; dd < 4; dd++)
                wr[dd] = *(const float2*)(&sm.w[d4 + dd][hg << 1]);
            #pragma unroll
            for (int j = 0; j < 4; j++) {
                float4 a = *(const float4*)(in + (size_t)(row0 + rg * 4 + j) * DDIM + dt + d4);
                acc[j].x = fmaf(a.x, wr[0].x, acc[j].x); acc[j].y = fmaf(a.x, wr[0].y, acc[j].y);
                acc[j].x = fmaf(a.y, wr[1].x, acc[j].x); acc[j].y = fmaf(a.y, wr[1].y, acc[j].y);
                acc[j].x = fmaf(a.z, wr[2].x, acc[j].x); acc[j].y = fmaf(a.z, wr[2].y, acc[j].y);
                acc[j].x = fmaf(a.w, wr[3].x, acc[j].x); acc[j].y = fmaf(a.w, wr[3].y, acc[j].y);
            }
        }
    }

    if (!iskey) {
        #pragma unroll
        for (int j = 0; j < 4; j++) {
            float2 o = make_float2(__builtin_amdgcn_exp2f(SCL * acc[j].x),
                                   __builtin_amdgcn_exp2f(SCL * acc[j].y));
            *(float2*)(Eq + (size_t)(row0 + rg * 4 + j) * HDIM + hbase + (hg << 1)) = o;
        }
    } else {
        __syncthreads();
        #pragma unroll
        for (int j = 0; j < 4; j++) {
            sm.t[(hg << 1) + 0][rg * 4 + j] = __builtin_amdgcn_exp2f(SCL * acc[j].x);
            sm.t[(hg << 1) + 1][rg * 4 + j] = __builtin_amdgcn_exp2f(SCL * acc[j].y);
        }
        __syncthreads();
        float* dst = Ek + (size_t)b * HDIM * KLEN + (size_t)hbase * KLEN + kc0;
        #pragma unroll
        for (int i = 0; i < 2; i++) {
            int idx = tid + 256 * i;
            int hh = idx >> 3, c = (idx & 7) << 2;
            float4 o = make_float4(sm.t[hh][c], sm.t[hh][c + 1],
                                   sm.t[hh][c + 2], sm.t[hh][c + 3]);
            *(float4*)(dst + (size_t)hh * KLEN + c) = o;
        }
    }
}

// ============ Scores + masked softmax ============
// Grid 512 (XCD-swizzled), 512 threads (8 waves). Block = (b, q-pair).
// Thread owns 2 contiguous k. tanh via r = rcp(Eq*Ek + 1): 1 trans + 2 fma
// per element. (Eq0,Eq1,w2) broadcast from LDS as one float4 per h.
__global__ __launch_bounds__(512) void score_kernel(
    const float* __restrict__ Eq, const float* __restrict__ Ek,
    const float* __restrict__ w_v, const int* __restrict__ valid_lens,
    float* __restrict__ p)
{
    __shared__ float4 eqw[HDIM];
    __shared__ float red0[8], red1[8];

    int tid = threadIdx.x, lane = tid & 63, wav = tid >> 6;
    int blk = blockIdx.x;
    int xcd = blk & 7, s = blk >> 3;
    int b = ((s >= 32) ? 8 : 0) + xcd;
    int qp = s & 31;
    int bq0 = b * 64 + qp * 2;
    int vlen = valid_lens[b];

    if (tid < HDIM) {
        float w2 = -2.0f * w_v[tid];
        eqw[tid] = make_float4(Eq[(size_t)bq0 * HDIM + tid],
                               Eq[(size_t)(bq0 + 1) * HDIM + tid], w2, 0.f);
    }
    __syncthreads();

    int k0 = tid << 1;
    float s00 = -1e30f, s01 = -1e30f, s10 = -1e30f, s11 = -1e30f;
    if (k0 < vlen) {
        const float* ekp = Ek + (size_t)b * HDIM * KLEN + k0;
        float a00 = 0.f, a01 = 0.f, a10 = 0.f, a11 = 0.f;
        #pragma unroll 4
        for (int h = 0; h < HDIM; h++) {
            float2 ek = *(const float2*)(ekp + (size_t)h * KLEN);
            float4 e  = eqw[h];
            a00 = fmaf(e.z, __builtin_amdgcn_rcpf(fmaf(e.x, ek.x, 1.f)), a00);
            a01 = fmaf(e.z, __builtin_amdgcn_rcpf(fmaf(e.x, ek.y, 1.f)), a01);
            a10 = fmaf(e.z, __builtin_amdgcn_rcpf(fmaf(e.y, ek.x, 1.f)), a10);
            a11 = fmaf(e.z, __builtin_amdgcn_rcpf(fmaf(e.y, ek.y, 1.f)), a11);
        }
        s00 = a00; s10 = a10;
        if (k0 + 1 < vlen) { s01 = a01; s11 = a11; }
    }

    float m0 = fmaxf(s00, s01), m1 = fmaxf(s10, s11);
    #pragma unroll
    for (int off = 32; off > 0; off >>= 1) {
        m0 = fmaxf(m0, __shfl_xor(m0, off, 64));
        m1 = fmaxf(m1, __shfl_xor(m1, off, 64));
    }
    if (lane == 0) { red0[wav] = m0; red1[wav] = m1; }
    __syncthreads();
    m0 = red0[0]; m1 = red1[0];
    #pragma unroll
    for (int i = 1; i < 8; i++) {
        m0 = fmaxf(m0, red0[i]);
        m1 = fmaxf(m1, red1[i]);
    }

    float e00 = __expf(s00 - m0), e01 = __expf(s01 - m0);   // masked -> exact 0
    float e10 = __expf(s10 - m1), e11 = __expf(s11 - m1);
    float t0 = e00 + e01, t1 = e10 + e11;
    #pragma unroll
    for (int off = 32; off > 0; off >>= 1) {
        t0 += __shfl_xor(t0, off, 64);
        t1 += __shfl_xor(t1, off, 64);
    }
    __syncthreads();
    if (lane == 0) { red0[wav] = t0; red1[wav] = t1; }
    __syncthreads();
    t0 = red0[0]; t1 = red1[0];
    #pragma unroll
    for (int i = 1; i < 8; i++) { t0 += red0[i]; t1 += red1[i]; }
    float inv0 = 1.0f / t0, inv1 = 1.0f / t1;

    float* p0 = p + (size_t)bq0 * KLEN + k0;
    *(float2*)(p0)        = make_float2(e00 * inv0, e01 * inv0);
    *(float2*)(p0 + KLEN) = make_float2(e10 * inv1, e11 * inv1);
}

// ============ attn @ V ============
// Grid 1024 = (16 b) x (8 q-tiles of 8) x (8 k-eighths of 128), XCD-swizzled.
// p-tile transposed into LDS once; inner loop = ds b64 broadcast + coalesced
// float4 V + 8 fma. Wave owns 2 q, lanes own d4. Always stores -> poison-safe.
__global__ __launch_bounds__(256) void av_kernel(
    const float* __restrict__ p, const float* __restrict__ values,
    const int* __restrict__ valid_lens, float* __restrict__ part)
{
    __shared__ float pt[128][10];   // [k][q], pad 8->10 keeps b64 alignment

    int blk = blockIdx.x;
    int xcd = blk & 7, s = blk >> 3;
    int b = ((s >> 6) << 3) | xcd;
    int r = s & 63, qt = r >> 3, kq = r & 7;
    int tid = threadIdx.x, lane = tid & 63, w = tid >> 6;
    int vlen = valid_lens[b];
    int kbeg = kq << 7;
    int kc = vlen - kbeg; kc = kc < 0 ? 0 : (kc > 128 ? 128 : kc);
    int kc4 = (kc + 3) & ~3;        // p is exactly 0 beyond vlen -> safe round-up
    int bq0 = b * 64 + qt * 8;

    {   // stage p[8q][128k] -> pt[k][q]
        int q = tid >> 5, k4 = (tid & 31) << 2;
        float4 pv = *(const float4*)(p + (size_t)(bq0 + q) * KLEN + kbeg + k4);
        pt[k4 + 0][q] = pv.x;
        pt[k4 + 1][q] = pv.y;
        pt[k4 + 2][q] = pv.z;
        pt[k4 + 3][q] = pv.w;
    }
    __syncthreads();

    const float* vb = values + ((size_t)b * KLEN + kbeg) * DDIM + (lane << 2);
    float4 a0 = make_float4(0.f, 0.f, 0.f, 0.f);
    float4 a1 = make_float4(0.f, 0.f, 0.f, 0.f);

    for (int k = 0; k < kc4; k += 4) {
        #pragma unroll
        for (int i = 0; i < 4; i++) {
            float2 pp = *(const float2*)(&pt[k + i][w << 1]);
            float4 v  = *(const float4*)(vb + (size_t)(k + i) * DDIM);
            a0.x = fmaf(pp.x, v.x, a0.x); a0.y = fmaf(pp.x, v.y, a0.y);
            a0.z = fmaf(pp.x, v.z, a0.z); a0.w = fmaf(pp.x, v.w, a0.w);
            a1.x = fmaf(pp.y, v.x, a1.x); a1.y = fmaf(pp.y, v.y, a1.y);
            a1.z = fmaf(pp.y, v.z, a1.z); a1.w = fmaf(pp.y, v.w, a1.w);
        }
    }
    float* d0 = part + ((size_t)kq * 1024 + bq0 + (w << 1)) * DDIM + (lane << 2);
    *(float4*)(d0)        = a0;
    *(float4*)(d0 + DDIM) = a1;
}

// ============ sum 8 k-partials ============
__global__ __launch_bounds__(256) void combine_kernel(
    const float* __restrict__ part, float* __restrict__ out)
{
    int i = blockIdx.x * 256 + threadIdx.x;        // 65536 float4 slots
    const float4* p4 = (const float4*)part;
    float4 a = p4[i];
    #pragma unroll
    for (int j = 1; j < 8; j++) {
        float4 v = p4[(size_t)j * 65536 + i];
        a.x += v.x; a.y += v.y; a.z += v.z; a.w += v.w;
    }
    ((float4*)out)[i] = a;
}

extern "C" void kernel_launch(void* const* d_in, const int* in_sizes, int n_in,
                              void* d_out, int out_size, void* d_ws, size_t ws_size,
                              hipStream_t stream) {
    const float* queries    = (const float*)d_in[0]; // [16,64,256]
    const float* keys       = (const float*)d_in[1]; // [16,1024,256]
    const float* values     = (const float*)d_in[2]; // [16,1024,256]
    const int*   valid_lens = (const int*)d_in[3];   // [16]
    const float* W_q        = (const float*)d_in[4]; // [256,128]
    const float* W_k        = (const float*)d_in[5]; // [256,128]
    const float* w_v        = (const float*)d_in[6]; // [128]

    float* Eq   = (float*)d_ws;            // 1024*128     = 512 KB
    float* Ek   = Eq + 131072;             // 16*128*1024  = 8 MB
    float* p    = Ek + 2097152;            // 1024*1024    = 4 MB
    float* part = Ek;                      // alias: Ek dead after score; 8 MB exact

    proj_kernel<<<1088, 256, 0, stream>>>(queries, keys, W_q, W_k, Eq, Ek);
    score_kernel<<<512, 512, 0, stream>>>(Eq, Ek, w_v, valid_lens, p);
    av_kernel<<<1024, 256, 0, stream>>>(p, values, valid_lens, part);
    combine_kernel<<<256, 256, 0, stream>>>(part, (float*)d_out);
}